// Round 7
// baseline (114.665 us; speedup 1.0000x reference)
//
#include <hip/hip_runtime.h>
#include <math.h>

#define BD 8
#define SD 1024
#define ID 64
#define OD 128
#define NBD 6
#define NGP 3          // g-pairs per j
#define SQ  2          // s per fused block

// ---- prep: P2c[(j*3+gp)*128+i] = {P[i,j,2gp], 1/p, P[i,j,2gp+1], 1/p'} ; MT/RT
__global__ __launch_bounds__(256) void prep_kernel(
    const float* __restrict__ P, const float* __restrict__ M,
    const float* __restrict__ resW,
    float4* __restrict__ P2c, float* __restrict__ MT, float* __restrict__ RT)
{
    const int idx = blockIdx.x * 256 + threadIdx.x;
    const int NP4 = OD * OD * NGP;                 // 49152
    if (idx < NP4) {
        const int i  = idx & 127;
        const int e  = idx >> 7;                   // j*3+gp
        const int j  = e / NGP;
        const int gp = e - j * NGP;
        const int g0 = gp * 2;
        const int base = i * (OD * NBD) + j * NBD; // P flat base == period base-2
        float4 v;
        v.x = P[base + g0];
        v.y = 1.0f / (float)(base + g0 + 2);
        v.z = P[base + g0 + 1];
        v.w = 1.0f / (float)(base + g0 + 3);
        P2c[idx] = v;
    } else if (idx < NP4 + OD * ID) {
        const int k = idx - NP4;
        const int i = k / ID, j = k - i * ID;
        MT[j * OD + i] = M[k];
    } else if (idx < NP4 + 2 * OD * ID) {
        const int k = idx - NP4 - OD * ID;
        const int i = k / ID, j = k - i * ID;
        RT[j * OD + i] = resW[k];
    }
}

// ---- fused: proj+LN (phase A, xn/res -> LDS) then Nk+residual -> out -------
// 512 threads, block handles s0..s0+1.
// Phase A: group ls=t>>8 (s-sub); within group i=t&127, mat=(t>>7)&1.
// Phase B: wave wv=t>>6 -> ls=wv>>2, ih=(wv>>1)&1, jh=wv&1; lane il=t&63.
__global__ __launch_bounds__(512, 4) void fused_kernel(
    const float* __restrict__ seq,    // (8,1024,64)
    const float* __restrict__ MT,     // (64,128) [j][i]
    const float* __restrict__ RT,     // (64,128) [j][i]
    const float* __restrict__ gamma,
    const float* __restrict__ beta,
    const float4* __restrict__ P2c,   // [(j*3+gp)*128 + i]
    float* __restrict__ out)          // (8,1024,128)
{
    const int t  = threadIdx.x;
    const int s0 = blockIdx.x * SQ;

    __shared__ __align__(16) float xn[SQ][OD][BD];   // 8 KB  [ls][j][b]
    __shared__ float res[SQ][BD][OD];                // 8 KB  [ls][b][i]
    __shared__ float red[SQ][2][16];
    __shared__ float stage[SQ][2][64][BD + 1];       // 9.2 KB, conflict-free

    // ================= Phase A: projections + LN =================
    {
        const int lsA = t >> 8;           // 0..1
        const int iA  = t & 127;
        const int mat = (t >> 7) & 1;     // wave-uniform
        const int sA  = s0 + lsA;

        float w[ID];
        {
            const float* __restrict__ WT = (mat ? RT : MT) + iA;
            #pragma unroll
            for (int j = 0; j < ID; ++j) w[j] = WT[j * OD];   // coalesced
        }

        float acc[BD];
        #pragma unroll
        for (int b = 0; b < BD; ++b) {
            const float* __restrict__ xp = &seq[(b * SD + sA) * ID]; // s_load
            float a0 = 0.f, a1 = 0.f;
            #pragma unroll
            for (int j = 0; j < ID; j += 2) {
                a0 = fmaf(xp[j],     w[j],     a0);
                a1 = fmaf(xp[j + 1], w[j + 1], a1);
            }
            acc[b] = a0 + a1;
        }

        if (mat == 0) {
            float sum[BD], ssq[BD];
            #pragma unroll
            for (int b = 0; b < BD; ++b) { sum[b] = acc[b]; ssq[b] = acc[b] * acc[b]; }
            #pragma unroll
            for (int m = 1; m < 64; m <<= 1) {
                #pragma unroll
                for (int b = 0; b < BD; ++b) {
                    sum[b] += __shfl_xor(sum[b], m, 64);
                    ssq[b] += __shfl_xor(ssq[b], m, 64);
                }
            }
            if ((t & 63) == 0) {
                const int wvh = (t >> 6) & 1;   // 0 or 1 within group
                #pragma unroll
                for (int b = 0; b < BD; ++b) {
                    red[lsA][wvh][b]     = sum[b];
                    red[lsA][wvh][8 + b] = ssq[b];
                }
            }
        } else {
            #pragma unroll
            for (int b = 0; b < BD; ++b) res[lsA][b][iA] = acc[b];
        }
        __syncthreads();

        if (mat == 0) {
            const float gm = gamma[iA];
            const float bt = beta[iA];
            float v[BD];
            #pragma unroll
            for (int b = 0; b < BD; ++b) {
                const float sm = red[lsA][0][b] + red[lsA][1][b];
                const float sq = red[lsA][0][8 + b] + red[lsA][1][8 + b];
                const float mu = sm * (1.0f / OD);
                const float vr = sq * (1.0f / OD) - mu * mu;
                const float rstd = rsqrtf(vr + 1e-5f);
                v[b] = (acc[b] - mu) * rstd * gm + bt;
            }
            *(float4*)&xn[lsA][iA][0] = make_float4(v[0], v[1], v[2], v[3]);
            *(float4*)&xn[lsA][iA][4] = make_float4(v[4], v[5], v[6], v[7]);
        }
    }
    __syncthreads();

    // ================= Phase B: Nk from LDS xn =================
    {
        const int wv = __builtin_amdgcn_readfirstlane(t >> 6);  // 0..7 uniform
        const int ls = wv >> 2;
        const int ih = (wv >> 1) & 1;
        const int jh = wv & 1;
        const int il = t & 63;
        const int i  = ih * 64 + il;
        const float sf = (float)(s0 + ls);

        float acc[BD];
        #pragma unroll
        for (int b = 0; b < BD; ++b) acc[b] = 0.f;

        const int j0 = jh * 64;
        #pragma unroll 2
        for (int j = 0; j < 64; ++j) {
            const int jj = j0 + j;
            const float4* __restrict__ Pp = &P2c[(jj * NGP) * OD + i]; // coalesced
            float wsum = 0.f;
            #pragma unroll
            for (int gp = 0; gp < NGP; ++gp) {
                const float4 pv = Pp[gp * OD];
                const float f0 = __builtin_amdgcn_fractf(sf * pv.y);  // revolutions
                const float f1 = __builtin_amdgcn_fractf(sf * pv.w);
                wsum = fmaf(pv.x, __builtin_amdgcn_cosf(f0), wsum);   // cos(2*pi*f)
                wsum = fmaf(pv.z, __builtin_amdgcn_cosf(f1), wsum);
            }
            const float4 xlo = *(const float4*)&xn[ls][jj][0];  // LDS broadcast
            const float4 xhi = *(const float4*)&xn[ls][jj][4];
            acc[0] = fmaf(xlo.x, wsum, acc[0]);
            acc[1] = fmaf(xlo.y, wsum, acc[1]);
            acc[2] = fmaf(xlo.z, wsum, acc[2]);
            acc[3] = fmaf(xlo.w, wsum, acc[3]);
            acc[4] = fmaf(xhi.x, wsum, acc[4]);
            acc[5] = fmaf(xhi.y, wsum, acc[5]);
            acc[6] = fmaf(xhi.z, wsum, acc[6]);
            acc[7] = fmaf(xhi.w, wsum, acc[7]);
        }

        if (jh) {
            #pragma unroll
            for (int b = 0; b < BD; ++b) stage[ls][ih][il][b] = acc[b];
        }
        __syncthreads();
        if (!jh) {
            #pragma unroll
            for (int b = 0; b < BD; ++b) {
                const float v = acc[b] + stage[ls][ih][il][b] + res[ls][b][i];
                out[(b * SD + (s0 + ls)) * OD + i] = v;   // single coalesced store
            }
        }
    }
}

extern "C" void kernel_launch(void* const* d_in, const int* in_sizes, int n_in,
                              void* d_out, int out_size, void* d_ws, size_t ws_size,
                              hipStream_t stream) {
    const float* seq   = (const float*)d_in[0];
    const float* M     = (const float*)d_in[1];
    const float* P     = (const float*)d_in[2];
    const float* resW  = (const float*)d_in[3];
    const float* gamma = (const float*)d_in[4];
    const float* beta  = (const float*)d_in[5];
    float* out = (float*)d_out;

    float4* P2c = (float4*)d_ws;                        // 768 KB
    float*  MT  = (float*)(P2c + OD * OD * NGP);        // 32 KB
    float*  RT  = MT + OD * ID;                         // 32 KB

    const int prep_elems = OD * OD * NGP + 2 * OD * ID; // 65536
    prep_kernel<<<dim3(prep_elems / 256), dim3(256), 0, stream>>>(
        P, M, resW, P2c, MT, RT);
    fused_kernel<<<dim3(SD / SQ), dim3(512), 0, stream>>>(
        seq, MT, RT, gamma, beta, P2c, out);
}

// Round 8
// 49.741 us; speedup vs baseline: 2.3052x; 2.3052x over previous
//
#include <hip/hip_runtime.h>
#include <math.h>

#define BD 8
#define SD 1024
#define ID 64
#define OD 128
#define NBD 6
#define NKG 4          // s per nk block

// ---- prep: P2[(j*6+g)*128+i] = P[i,j,g] ; MT/RT transposed weights ---------
__global__ __launch_bounds__(256) void prep_kernel(
    const float* __restrict__ P, const float* __restrict__ M,
    const float* __restrict__ resW,
    float* __restrict__ P2, float* __restrict__ MT, float* __restrict__ RT)
{
    const int idx = blockIdx.x * 256 + threadIdx.x;
    const int NP = OD * OD * NBD;                  // 98304
    if (idx < NP) {
        const int i = idx / (OD * NBD);
        const int r = idx - i * (OD * NBD);        // j*6+g
        P2[r * OD + i] = P[idx];
    } else if (idx < NP + OD * ID) {
        const int k = idx - NP;
        const int i = k / ID, j = k - i * ID;
        MT[j * OD + i] = M[k];
    } else if (idx < NP + 2 * OD * ID) {
        const int k = idx - NP - OD * ID;
        const int i = k / ID, j = k - i * ID;
        RT[j * OD + i] = resW[k];
    }
}

// ---- Kernel A: weight-stationary proj + LN -> xn_g ; residual -> out -------
__global__ __launch_bounds__(256) void ln_kernel(
    const float* __restrict__ seq,    // (8,1024,64)
    const float* __restrict__ MT,     // (64,128) [j][i]
    const float* __restrict__ RT,     // (64,128) [j][i]
    const float* __restrict__ gamma,
    const float* __restrict__ beta,
    float* __restrict__ xn_g,         // (1024,128,8) [s][j][b]
    float* __restrict__ out)          // (8,1024,128) gets residual
{
    const int t   = threadIdx.x;
    const int s   = blockIdx.x;
    const int i   = t & 127;
    const int mat = t >> 7;           // wave-uniform
    __shared__ float red[2][16];

    float w[ID];
    {
        const float* __restrict__ WT = (mat ? RT : MT) + i;
        #pragma unroll
        for (int j = 0; j < ID; ++j) w[j] = WT[j * OD];   // coalesced
    }
    const float gm = gamma[i];
    const float bt = beta[i];

    float acc[BD];
    #pragma unroll
    for (int b = 0; b < BD; ++b) {
        const float* __restrict__ xp = &seq[(b * SD + s) * ID];  // uniform -> s_load
        float a0 = 0.f, a1 = 0.f;
        #pragma unroll
        for (int j = 0; j < ID; j += 2) {
            a0 = fmaf(xp[j],     w[j],     a0);
            a1 = fmaf(xp[j + 1], w[j + 1], a1);
        }
        acc[b] = a0 + a1;
    }

    if (mat == 0) {
        float sum[BD], ssq[BD];
        #pragma unroll
        for (int b = 0; b < BD; ++b) { sum[b] = acc[b]; ssq[b] = acc[b] * acc[b]; }
        #pragma unroll
        for (int m = 1; m < 64; m <<= 1) {
            #pragma unroll
            for (int b = 0; b < BD; ++b) {
                sum[b] += __shfl_xor(sum[b], m, 64);
                ssq[b] += __shfl_xor(ssq[b], m, 64);
            }
        }
        if ((t & 63) == 0) {
            const int wv = t >> 6;
            #pragma unroll
            for (int b = 0; b < BD; ++b) {
                red[wv][b]     = sum[b];
                red[wv][8 + b] = ssq[b];
            }
        }
    }
    __syncthreads();

    if (mat == 0) {
        float xn[BD];
        #pragma unroll
        for (int b = 0; b < BD; ++b) {
            const float sm = red[0][b] + red[1][b];
            const float sq = red[0][8 + b] + red[1][8 + b];
            const float mu = sm * (1.0f / OD);
            const float vr = sq * (1.0f / OD) - mu * mu;
            const float rstd = rsqrtf(vr + 1e-5f);
            xn[b] = (acc[b] - mu) * rstd * gm + bt;
        }
        float* __restrict__ dst = &xn_g[(s * OD + i) * BD];
        *(float4*)&dst[0] = make_float4(xn[0], xn[1], xn[2], xn[3]);
        *(float4*)&dst[4] = make_float4(xn[4], xn[5], xn[6], xn[7]);
    } else {
        #pragma unroll
        for (int b = 0; b < BD; ++b)
            out[(b * SD + s) * OD + i] = acc[b];
    }
}

// ---- Kernel B: Nk, out += Nk -----------------------------------------------
// 512 threads = 8 waves: jq = wave (16 j each, all 128 j in-block -> no races).
// il = t&63 -> i = ih*64+il. NKG=4 s in registers; xn slice staged in LDS.
__global__ __launch_bounds__(512, 4) void nk_kernel(
    const float* __restrict__ P2,     // [j][g][i]
    const float* __restrict__ xn_g,   // (1024,128,8) [s][j][b]
    float* __restrict__ out)          // (8,1024,128)
{
    const int s0 = blockIdx.x * NKG;
    const int ih = blockIdx.y;
    const int t  = threadIdx.x;
    const int il = t & 63;
    const int jq = __builtin_amdgcn_readfirstlane(t >> 6);  // 0..7, uniform
    const int i  = ih * 64 + il;

    __shared__ __align__(16) float xn[NKG][OD][BD];   // 16 KB [ls][j][b]
    __shared__ float stage[8][64][BD + 1];            // 18.4 KB, conflict-free

    // stage xn for the block's 4 s (contiguous, coalesced)
    for (int o = t; o < NKG * OD * BD; o += 512)
        ((float*)xn)[o] = xn_g[s0 * OD * BD + o];
    __syncthreads();

    float acc[NKG][BD];
    #pragma unroll
    for (int ls = 0; ls < NKG; ++ls)
        #pragma unroll
        for (int b = 0; b < BD; ++b) acc[ls][b] = 0.f;

    const float pbase = (float)(i * (OD * NBD) + 2);  // exact int in f32
    const int j0 = jq * 16;

    #pragma unroll 2
    for (int j = 0; j < 16; ++j) {
        const int jj = j0 + j;
        const float* __restrict__ Pp = &P2[(jj * NBD) * OD + i];  // coalesced
        float Pv[NBD], rp[NBD];
        #pragma unroll
        for (int g = 0; g < NBD; ++g) {
            Pv[g] = Pp[g * OD];
            rp[g] = __builtin_amdgcn_rcpf(pbase + (float)(jj * NBD + g)); // /4 s
        }
        #pragma unroll
        for (int ls = 0; ls < NKG; ++ls) {
            const float sf = (float)(s0 + ls);
            float wsum = 0.f;
            #pragma unroll
            for (int g = 0; g < NBD; ++g) {
                const float fr = __builtin_amdgcn_fractf(sf * rp[g]);  // revolutions
                wsum = fmaf(Pv[g], __builtin_amdgcn_cosf(fr), wsum);   // cos(2*pi*fr)
            }
            const float4 xlo = *(const float4*)&xn[ls][jj][0];  // LDS broadcast
            const float4 xhi = *(const float4*)&xn[ls][jj][4];
            acc[ls][0] = fmaf(xlo.x, wsum, acc[ls][0]);
            acc[ls][1] = fmaf(xlo.y, wsum, acc[ls][1]);
            acc[ls][2] = fmaf(xlo.z, wsum, acc[ls][2]);
            acc[ls][3] = fmaf(xlo.w, wsum, acc[ls][3]);
            acc[ls][4] = fmaf(xhi.x, wsum, acc[ls][4]);
            acc[ls][5] = fmaf(xhi.y, wsum, acc[ls][5]);
            acc[ls][6] = fmaf(xhi.z, wsum, acc[ls][6]);
            acc[ls][7] = fmaf(xhi.w, wsum, acc[ls][7]);
        }
    }

    // ---- reduce 8 jq partials per s, out += Nk ----
    #pragma unroll
    for (int ls = 0; ls < NKG; ++ls) {
        __syncthreads();
        #pragma unroll
        for (int b = 0; b < BD; ++b) stage[jq][il][b] = acc[ls][b];
        __syncthreads();
        {
            const int ii = t & 63;     // coalesced store dimension
            const int b  = t >> 6;
            float v = 0.f;
            #pragma unroll
            for (int q = 0; q < 8; ++q) v += stage[q][ii][b];
            out[(b * SD + (s0 + ls)) * OD + ih * 64 + ii] += v;
        }
    }
}

extern "C" void kernel_launch(void* const* d_in, const int* in_sizes, int n_in,
                              void* d_out, int out_size, void* d_ws, size_t ws_size,
                              hipStream_t stream) {
    const float* seq   = (const float*)d_in[0];
    const float* M     = (const float*)d_in[1];
    const float* P     = (const float*)d_in[2];
    const float* resW  = (const float*)d_in[3];
    const float* gamma = (const float*)d_in[4];
    const float* beta  = (const float*)d_in[5];
    float* out = (float*)d_out;

    float* xn_g = (float*)d_ws;                    // 4 MB
    float* P2   = xn_g + SD * OD * BD;             // 384 KB
    float* MT   = P2 + OD * OD * NBD;              // 32 KB
    float* RT   = MT + OD * ID;                    // 32 KB

    const int prep_elems = OD * OD * NBD + 2 * OD * ID;  // 114688
    prep_kernel<<<dim3((prep_elems + 255) / 256), dim3(256), 0, stream>>>(
        P, M, resW, P2, MT, RT);
    ln_kernel<<<dim3(SD), dim3(256), 0, stream>>>(seq, MT, RT, gamma, beta,
                                                  xn_g, out);
    nk_kernel<<<dim3(SD / NKG, 2), dim3(512), 0, stream>>>(P2, xn_g, out);
}